// Round 7
// baseline (120.158 us; speedup 1.0000x reference)
//
#include <hip/hip_runtime.h>

// inputs: [M=4096, N=16384] fp32 logits; targets: [M] int32; k = int(0.01*(N-1)) = 163
#define M        4096
#define N        16384
#define K_SEL    163
#define DELTA_W  5.0f
#define NT       256
#define RPB      4             // rows per block in kernel A
#define CAP      512           // per-row candidate capacity (Gaussian: mean 373, sd 19)
#define SCALE    4096.0f       // fixed-point for hard-negative sum (order-independent)
#define GSCALE   1048576.0     // 2^20 fixed-point for the global row-loss sum
#define THRESH   2.0f          // E[count(x>=2)] = 373 per row; 11 sigma above K_SEL

typedef float vfloat4 __attribute__((ext_vector_type(4)));

// Order-preserving float<->uint32 key (ascending float <-> ascending key)
__device__ __forceinline__ unsigned f2key(float x) {
    unsigned u = __float_as_uint(x);
    return u ^ ((unsigned)((int)u >> 31) | 0x80000000u);
}
__device__ __forceinline__ float key2f(unsigned k) {
    unsigned u = k ^ (~(unsigned)((int)k >> 31) | 0x80000000u);
    return __uint_as_float(u);
}
__device__ __forceinline__ void wave_lgkm_wait() {
    asm volatile("s_waitcnt lgkmcnt(0)" ::: "memory");
}

// ---------- Kernel A: double-buffered streaming filter, 4 rows per block ----------
// Batch b (0..7): row r=b>>1, half h=b&1. Pipeline: load(b) overlaps consume(b-2);
// in-flight never drains between batches.
#define LOAD_BATCH(BUF, Bc)                                                   \
    do { const int r_ = (Bc) >> 1, h_ = (Bc) & 1;                             \
        _Pragma("unroll")                                                     \
        for (int u = 0; u < 8; ++u)                                           \
            BUF[u] = rp4[r_][(h_ * 8 + u) * NT + tid];                        \
    } while (0)

#define CONSUME_BATCH(BUF, Bc)                                                \
    do { const int r_ = (Bc) >> 1, h_ = (Bc) & 1;                             \
        _Pragma("unroll")                                                     \
        for (int u = 0; u < 8; ++u) {                                         \
            const int col = ((h_ * 8 + u) * NT + tid) * 4;                    \
            float mx = fmaxf(fmaxf(BUF[u].x, BUF[u].y),                       \
                             fmaxf(BUF[u].z, BUF[u].w));                      \
            if (mx >= THRESH) {                                               \
                _Pragma("unroll")                                             \
                for (int j = 0; j < 4; ++j) {                                 \
                    float x = BUF[u][j];                                      \
                    if (x >= THRESH && (col + j) != tcol[r_]) {               \
                        unsigned idx = atomicAdd(&s_n[r_], 1u);               \
                        if (idx < CAP) s_list[r_][idx] = f2key(x);            \
                    }                                                         \
                }                                                             \
            }                                                                 \
        }                                                                     \
    } while (0)

__global__ __launch_bounds__(NT) void stream_candidates(
    const float* __restrict__ inp, const int* __restrict__ tgt,
    unsigned* __restrict__ cnt, unsigned* __restrict__ list,
    unsigned long long* __restrict__ acc)
{
    const int blk = blockIdx.x;
    const int tid = threadIdx.x;
    if (blk == 0 && tid == 0) *acc = 0ull;   // A precedes B in-stream: safe zero

    __shared__ unsigned s_list[RPB][CAP];    // 8 KiB
    __shared__ unsigned s_n[RPB];
    if (tid < RPB) s_n[tid] = 0u;
    __syncthreads();

    const int row0 = blk * RPB;
    const vfloat4* rp4[RPB];
    int tcol[RPB];
    #pragma unroll
    for (int r = 0; r < RPB; ++r) {
        rp4[r]  = reinterpret_cast<const vfloat4*>(inp + (size_t)(row0 + r) * N);
        tcol[r] = tgt[row0 + r];
    }

    vfloat4 bufA[8], bufB[8];
    LOAD_BATCH(bufA, 0);
    LOAD_BATCH(bufB, 1);
    CONSUME_BATCH(bufA, 0); LOAD_BATCH(bufA, 2);
    CONSUME_BATCH(bufB, 1); LOAD_BATCH(bufB, 3);
    CONSUME_BATCH(bufA, 2); LOAD_BATCH(bufA, 4);
    CONSUME_BATCH(bufB, 3); LOAD_BATCH(bufB, 5);
    CONSUME_BATCH(bufA, 4); LOAD_BATCH(bufA, 6);
    CONSUME_BATCH(bufB, 5); LOAD_BATCH(bufB, 7);
    CONSUME_BATCH(bufA, 6);
    CONSUME_BATCH(bufB, 7);

    __syncthreads();
    #pragma unroll
    for (int r = 0; r < RPB; ++r) {
        const unsigned n = s_n[r];           // exact count (never capped)
        if (tid == 0) cnt[row0 + r] = n;
        unsigned* rl = list + (size_t)(row0 + r) * CAP;
        const unsigned lim = (n < CAP) ? n : CAP;
        for (unsigned i = tid; i < lim; i += NT) rl[i] = s_list[r][i];
    }
}

// ---------- Kernel B: wave-per-row radix select, zero __syncthreads ----------
__global__ __launch_bounds__(NT) void select_and_loss(
    const float* __restrict__ inp, const int* __restrict__ tgt,
    const unsigned* __restrict__ cnt, const unsigned* __restrict__ list,
    unsigned long long* __restrict__ acc)
{
    __shared__ unsigned hist_all[4][256];    // wave-private 1 KiB each
    const int lane = threadIdx.x & 63;
    const int wv   = threadIdx.x >> 6;
    const int row  = blockIdx.x * 4 + wv;
    unsigned* hist = hist_all[wv];
    const float* rp = inp + (size_t)row * N;
    const int target = tgt[row];
    const unsigned CHI = cnt[row];

    unsigned prefix = 0u, kr = K_SEL;
    float loss = 0.0f;
    bool have = false;

    if (CHI >= K_SEL && CHI <= CAP) {
        const unsigned* gl = list + (size_t)row * CAP;
        unsigned keys[8];
        #pragma unroll
        for (int it = 0; it < 8; ++it) {
            unsigned i = lane + it * 64u;
            keys[it] = (i < CHI) ? gl[i] : 0u;        // pad with min-key
        }
        for (int pass = 0; pass < 4; ++pass) {
            *reinterpret_cast<uint4*>(&hist[lane * 4]) = make_uint4(0, 0, 0, 0);
            wave_lgkm_wait();
            const int shift = 24 - 8 * pass;
            #pragma unroll
            for (int it = 0; it < 8; ++it) {
                unsigned k = keys[it];
                bool m = (lane + it * 64u < CHI) &&
                         (pass == 0 || (k >> (shift + 8)) == prefix);
                if (m) atomicAdd(&hist[(k >> shift) & 0xFFu], 1u);
            }
            wave_lgkm_wait();
            uint4 h = *reinterpret_cast<const uint4*>(&hist[lane * 4]);
            unsigned hb[4] = {h.x, h.y, h.z, h.w};
            unsigned s_local = hb[0] + hb[1] + hb[2] + hb[3];
            unsigned suf = s_local;                   // suffix-scan over lanes
            #pragma unroll
            for (int off = 1; off < 64; off <<= 1) {
                unsigned o = __shfl_down(suf, off);
                suf += (lane + off < 64) ? o : 0u;
            }
            unsigned acc_above = suf - s_local;
            int foundc = -1; unsigned f_abv = 0;
            #pragma unroll
            for (int c = 3; c >= 0; --c) {
                unsigned S = acc_above + hb[c];
                if (acc_above < kr && S >= kr) { foundc = c; f_abv = acc_above; }
                acc_above = S;
            }
            bool win = (foundc >= 0);
            unsigned long long bal = __ballot(win);
            int wl = __ffsll((long long)bal) - 1;
            unsigned np = win ? ((prefix << 8) | (unsigned)(lane * 4 + foundc)) : 0u;
            unsigned nk = win ? (kr - f_abv) : 0u;
            prefix = __shfl(np, wl);
            kr     = __shfl(nk, wl);
        }
        const unsigned tkey = prefix, krem = kr;

        int facc = 0;                                 // fixed-point, order-independent
        #pragma unroll
        for (int it = 0; it < 8; ++it) {
            unsigned k = keys[it];
            if ((lane + it * 64u) < CHI && k > tkey) {
                float w = key2f(k) + 1.0f;
                facc += (int)(w * w * SCALE + 0.5f);
            }
        }
        #pragma unroll
        for (int off = 32; off > 0; off >>= 1) facc += __shfl_down(facc, off);
        if (lane == 0) {
            float tv    = key2f(tkey) + 1.0f;
            float total = (float)facc * (1.0f / SCALE) + (float)krem * tv * tv;
            float pos   = rp[target];
            float pd    = pos - 1.0f;
            loss = DELTA_W * pd * pd + total * (1.0f / (float)K_SEL);
            have = true;
        }
    } else {
        // fallback: exact full-row radix (never taken for Gaussian bench data)
        for (int pass = 0; pass < 4; ++pass) {
            *reinterpret_cast<uint4*>(&hist[lane * 4]) = make_uint4(0, 0, 0, 0);
            wave_lgkm_wait();
            const int shift = 24 - 8 * pass;
            for (int it = 0; it < N / 64; ++it) {
                int i = lane + it * 64;
                unsigned k = f2key(rp[i]);
                if (i == target) k = 0u;
                bool m = (pass == 0) || ((k >> (shift + 8)) == prefix);
                if (m) atomicAdd(&hist[(k >> shift) & 0xFFu], 1u);
            }
            wave_lgkm_wait();
            uint4 h = *reinterpret_cast<const uint4*>(&hist[lane * 4]);
            unsigned hb[4] = {h.x, h.y, h.z, h.w};
            unsigned s_local = hb[0] + hb[1] + hb[2] + hb[3];
            unsigned suf = s_local;
            #pragma unroll
            for (int off = 1; off < 64; off <<= 1) {
                unsigned o = __shfl_down(suf, off);
                suf += (lane + off < 64) ? o : 0u;
            }
            unsigned acc_above = suf - s_local;
            int foundc = -1; unsigned f_abv = 0;
            #pragma unroll
            for (int c = 3; c >= 0; --c) {
                unsigned S = acc_above + hb[c];
                if (acc_above < kr && S >= kr) { foundc = c; f_abv = acc_above; }
                acc_above = S;
            }
            bool win = (foundc >= 0);
            unsigned long long bal = __ballot(win);
            int wl = __ffsll((long long)bal) - 1;
            unsigned np = win ? ((prefix << 8) | (unsigned)(lane * 4 + foundc)) : 0u;
            unsigned nk = win ? (kr - f_abv) : 0u;
            prefix = __shfl(np, wl);
            kr     = __shfl(nk, wl);
        }
        const unsigned tkey = prefix, krem = kr;

        int facc = 0;
        for (int it = 0; it < N / 64; ++it) {
            int i = lane + it * 64;
            unsigned k = f2key(rp[i]);
            if (i == target) k = 0u;
            if (k > tkey) { float w = key2f(k) + 1.0f; facc += (int)(w * w * SCALE + 0.5f); }
        }
        #pragma unroll
        for (int off = 32; off > 0; off >>= 1) facc += __shfl_down(facc, off);
        if (lane == 0) {
            float tv    = key2f(tkey) + 1.0f;
            float total = (float)facc * (1.0f / SCALE) + (float)krem * tv * tv;
            float pos   = rp[target];
            float pd    = pos - 1.0f;
            loss = DELTA_W * pd * pd + total * (1.0f / (float)K_SEL);
            have = true;
        }
    }

    // deterministic global mean: 2^20 fixed-point integer accumulate (loss >= 0)
    if (have) {
        unsigned long long q = (unsigned long long)((double)loss * GSCALE + 0.5);
        atomicAdd(acc, q);
    }
}

__global__ void finalize(const unsigned long long* __restrict__ acc,
                         float* __restrict__ out)
{
    if (threadIdx.x == 0)
        out[0] = (float)((double)(*acc) / (GSCALE * (double)M));
}

extern "C" void kernel_launch(void* const* d_in, const int* in_sizes, int n_in,
                              void* d_out, int out_size, void* d_ws, size_t ws_size,
                              hipStream_t stream) {
    const float* inp = (const float*)d_in[0];
    const int*   tgt = (const int*)d_in[1];
    float* out = (float*)d_out;

    unsigned* cnt  = (unsigned*)d_ws;                               // 16 KiB
    unsigned* list = (unsigned*)((char*)d_ws + 16 * 1024);          // 8 MiB
    unsigned long long* acc =
        (unsigned long long*)((char*)d_ws + 16 * 1024 + (size_t)M * CAP * 4);

    stream_candidates<<<M / RPB, NT, 0, stream>>>(inp, tgt, cnt, list, acc);
    select_and_loss<<<M / 4, NT, 0, stream>>>(inp, tgt, cnt, list, acc);
    finalize<<<1, 64, 0, stream>>>(acc, out);
}